// Round 20
// baseline (385.765 us; speedup 1.0000x reference)
//
#include <hip/hip_runtime.h>
#include <hip/hip_fp16.h>

#define NN 100000
#define NE 1600000
#define SCAN_BLK 1024
#define NBLK ((NN + SCAN_BLK - 1) / SCAN_BLK)   // 98

#define EB 6144                                  // edges per bucket-block chunk
#define NBE ((NE + EB - 1) / EB)                 // 261
#define BSH 10                                   // 1024-node buckets
#define NBUCK ((NN + 1023) >> BSH)               // 98
#define BCAP 18432                               // pairs cap/bucket (exp 16327, sd ~127)

// ---------------- structure precompute ----------------

__global__ void k_init(int* __restrict__ bcur) {
    int i = blockIdx.x * blockDim.x + threadIdx.x;
    if (i < NBUCK) bcur[i] = i * BCAP;
}

// chunk edges -> per-bucket contiguous runs of (dst,src) pairs
__global__ __launch_bounds__(256) void k_bucket(
    const int* __restrict__ ei, int* __restrict__ bcur,
    long long* __restrict__ pairs, int nE) {
    __shared__ int cnt[NBUCK];
    __shared__ int sc[NBUCK];
    __shared__ int rc[NBUCK];
    __shared__ int gbase[NBUCK];
    __shared__ int tmp[256];
    __shared__ long long st[EB];

    int base = blockIdx.x * EB;
    int lim = nE - base; if (lim > EB) lim = EB;
    int tid = threadIdx.x;

    for (int i = tid; i < NBUCK; i += 256) cnt[i] = 0;
    __syncthreads();
    for (int i = tid; i < lim; i += 256) {
        int d = ei[nE + base + i];
        atomicAdd(&cnt[d >> BSH], 1);
    }
    __syncthreads();
    {
        int v = (tid < NBUCK) ? cnt[tid] : 0;
        tmp[tid] = v;
        __syncthreads();
        for (int off = 1; off < 256; off <<= 1) {
            int add = (tid >= off) ? tmp[tid - off] : 0;
            __syncthreads();
            tmp[tid] += add;
            __syncthreads();
        }
        if (tid < NBUCK) {
            int e = tmp[tid] - v;
            sc[tid] = e;
            rc[tid] = e;
            gbase[tid] = (v > 0) ? atomicAdd(&bcur[tid], v) : 0;
        }
    }
    __syncthreads();
    for (int i = tid; i < lim; i += 256) {
        int s = ei[base + i];
        int d = ei[nE + base + i];
        int p = atomicAdd(&rc[d >> BSH], 1);
        st[p] = ((long long)d << 32) | (unsigned int)s;
    }
    __syncthreads();
    for (int i = tid; i < lim; i += 256) {
        long long pr = st[i];
        int b = (int)(pr >> 32) >> BSH;
        pairs[gbase[b] + (i - sc[b])] = pr;
    }
}

// per-bucket LDS histogram -> coalesced non-atomic deg write
__global__ __launch_bounds__(256) void k_count2(
    const long long* __restrict__ pairs, const int* __restrict__ bcur,
    int* __restrict__ deg) {
    __shared__ int cnt[1 << BSH];
    int b = blockIdx.x;
    int gb = b * BCAP;
    int m = bcur[b] - gb;
    for (int i = threadIdx.x; i < (1 << BSH); i += 256) cnt[i] = 0;
    __syncthreads();
    for (int i = threadIdx.x; i < m; i += 256) {
        int d = (int)(pairs[gb + i] >> 32);
        atomicAdd(&cnt[d & ((1 << BSH) - 1)], 1);
    }
    __syncthreads();
    int base = b << BSH;
    for (int i = threadIdx.x; i < (1 << BSH); i += 256) {
        int v = base + i;
        if (v < NN) deg[v] = cnt[i];
    }
}

// scan over PADDED degrees: pdeg = (deg+7)&~7
__global__ __launch_bounds__(SCAN_BLK) void k_scan1(
    const int* __restrict__ deg, int* __restrict__ exc, int* __restrict__ bsum, int n) {
    __shared__ int sh[SCAN_BLK];
    int tid = threadIdx.x;
    int i = blockIdx.x * SCAN_BLK + tid;
    int v = (i < n) ? ((deg[i] + 7) & ~7) : 0;
    sh[tid] = v;
    __syncthreads();
    for (int off = 1; off < SCAN_BLK; off <<= 1) {
        int add = (tid >= off) ? sh[tid - off] : 0;
        __syncthreads();
        sh[tid] += add;
        __syncthreads();
    }
    if (i < n) exc[i] = sh[tid] - v;
    if (tid == SCAN_BLK - 1) bsum[blockIdx.x] = sh[tid];
}

__global__ __launch_bounds__(128) void k_scan2(int* __restrict__ bsum, int nb) {
    __shared__ int sh[128];
    int tid = threadIdx.x;
    int v = (tid < nb) ? bsum[tid] : 0;
    sh[tid] = v;
    __syncthreads();
    for (int off = 1; off < 128; off <<= 1) {
        int add = (tid >= off) ? sh[tid - off] : 0;
        __syncthreads();
        sh[tid] += add;
        __syncthreads();
    }
    if (tid < nb) bsum[tid] = sh[tid] - v;  // exclusive
}

// rowptr (padded) + dinv + hd0 = x*dinv (fp16) + dummy row + total
__global__ __launch_bounds__(SCAN_BLK) void k_scan3(
    const int* __restrict__ exc, const int* __restrict__ bsum,
    const int* __restrict__ deg, const float* __restrict__ x,
    int* __restrict__ rowptr, float* __restrict__ dinv,
    __half2* __restrict__ hd0, int n) {
    int i = blockIdx.x * SCAN_BLK + threadIdx.x;
    if (i >= n) return;
    int r = exc[i] + bsum[blockIdx.x];
    rowptr[i] = r;
    float dv = rsqrtf((float)(deg[i] + 1));  // +1 = self loop
    dinv[i] = dv;
    hd0[i] = __floats2half2_rn(x[2 * i] * dv, x[2 * i + 1] * dv);
    if (i == n - 1) rowptr[n] = r + ((deg[i] + 7) & ~7);
    if (i == 0) hd0[n] = __floats2half2_rn(0.f, 0.f);  // dummy row (pad target)
}

// per-bucket scatter with LDS cursors; then write pad entries (src = NN dummy)
__global__ __launch_bounds__(256) void k_fill3(
    const long long* __restrict__ pairs, const int* __restrict__ bcur,
    const int* __restrict__ rowptr, int* __restrict__ csr_src) {
    __shared__ int lcur[1 << BSH];
    int b = blockIdx.x;
    int gb = b * BCAP;
    int m = bcur[b] - gb;
    int base = b << BSH;
    for (int i = threadIdx.x; i < (1 << BSH); i += 256) {
        int v = base + i;
        lcur[i] = (v < NN) ? rowptr[v] : 0;
    }
    __syncthreads();
    for (int i = threadIdx.x; i < m; i += 256) {
        long long pr = pairs[gb + i];
        int d = (int)(pr >> 32);
        int s = (int)(pr & 0xffffffffLL);
        int pos = atomicAdd(&lcur[d & ((1 << BSH) - 1)], 1);
        csr_src[pos] = s;
    }
    __syncthreads();
    for (int i = threadIdx.x; i < (1 << BSH); i += 256) {
        int v = base + i;
        if (v < NN) {
            int e = lcur[i];          // rowptr[v] + deg[v]
            int pe = rowptr[v + 1];   // padded end
            for (; e < pe; ++e) csr_src[e] = NN;
        }
    }
}

// ---------------- layer kernels ----------------
// agg[v] = dinv[v] * (sum_j hd_in[src_j] + hd_in[v]) ; o = agg@W + b
// hd_out = relu(o)*dinv (fp16)   |  LAST: out = o + xorig (fp32)
// Rows padded to x8 with dummy src NN (zero row). All hot-path index math
// is 32-bit int (max index 3.2M) -> saddr-form loads, no 64-bit VALU.

// L1: DIN=2 (4B rows). ONE WAVE PER NODE: 64 lanes = 64 edge slots, the
// whole row set covered by ONE masked gather instruction (deg<=64 typical).
__global__ __launch_bounds__(256) void k_layer1(
    const int* __restrict__ rowptr, const int* __restrict__ csr_src,
    const __half2* __restrict__ hd0, const float* __restrict__ Wg,
    const float* __restrict__ bg, const float* __restrict__ dinv,
    __half* __restrict__ hd1, int n) {
    int lane = threadIdx.x & 63;
    int v = blockIdx.x * 4 + (threadIdx.x >> 6);
    if (v > n) return;
    if (v == n) {                           // dummy row for next layer's pads
        if (lane < 16) hd1[v * 16 + lane] = __float2half(0.f);
        return;
    }
    int lo = rowptr[v], hi = rowptr[v + 1];
    const uint* hp = (const uint*)hd0;
    int j = lo + lane;
    int sc = csr_src[j];                    // slack-safe unconditional load
    int s = (j < hi) ? sc : NN;
    uint u = hp[s];
    float2 f = __half22float2(*(const __half2*)&u);
    float a0 = f.x, a1 = f.y;
    for (int jb = lo + 64; jb < hi; jb += 64) {   // essentially never taken
        int jj = jb + lane;
        int s2 = (jj < hi) ? csr_src[jj] : NN;
        uint u2 = hp[s2];
        float2 f2v = __half22float2(*(const __half2*)&u2);
        a0 += f2v.x; a1 += f2v.y;
    }
#pragma unroll
    for (int off = 1; off < 64; off <<= 1) {
        a0 += __shfl_xor(a0, off, 64);
        a1 += __shfl_xor(a1, off, 64);
    }
    float dv = dinv[v];
    float2 hs = __half22float2(hd0[v]);
    a0 = (a0 + hs.x) * dv;
    a1 = (a1 + hs.y) * dv;
    if (lane < 16) {
        float o = bg[lane] + a0 * Wg[lane] + a1 * Wg[16 + lane];  // W (2,16) rm
        hd1[v * 16 + lane] = __float2half(fmaxf(o, 0.f) * dv);
    }
}

// Unrolled-burst layer + replica-split epilogue (DIN=32) with packed stores.
template <int DIN, int DOUT, bool RELU, bool LAST>
__global__ __launch_bounds__(256) void k_layerU(
    const int* __restrict__ rowptr, const int* __restrict__ csr_src,
    const __half* __restrict__ hd_in, const float* __restrict__ Wg,
    const float* __restrict__ bg, const float* __restrict__ dinv,
    const float* __restrict__ xorig, __half* __restrict__ hout_h,
    float* __restrict__ hout_f, int n) {
    constexpr int PQ = DIN / 2;           // uints per row
    int lane = threadIdx.x & 63;

    int v = blockIdx.x * 4 + (threadIdx.x >> 6);
    if (v > n) return;
    if (v == n) {                          // dummy row for next layer's pads
        if (!LAST && lane < DOUT) hout_h[v * DOUT + lane] = __float2half(0.f);
        return;
    }
    int q = lane & (PQ - 1);
    int lo = rowptr[v], hi = rowptr[v + 1];   // (hi-lo)%8==0
    int nch = (hi - lo) >> 3;
    const uint* hp = (const uint*)hd_in;
    float accx = 0.f, accy = 0.f;

    if constexpr (DIN == 32) {
        int el = lane >> 4;                // 4 edge slots; 2 edges/chunk/lane
        int b0 = lo + el;
        int sA0 = csr_src[b0 +  0], sB0 = csr_src[b0 +  4];
        int sA1 = csr_src[b0 +  8], sB1 = csr_src[b0 + 12];
        int sA2 = csr_src[b0 + 16], sB2 = csr_src[b0 + 20];
        int sA3 = csr_src[b0 + 24], sB3 = csr_src[b0 + 28];
        if (nch < 1) { sA0 = NN; sB0 = NN; }
        if (nch < 2) { sA1 = NN; sB1 = NN; }
        if (nch < 3) { sA2 = NN; sB2 = NN; }
        if (nch < 4) { sA3 = NN; sB3 = NN; }
        uint uA0 = hp[sA0 * 16 + q], uB0 = hp[sB0 * 16 + q];
        uint uA1 = hp[sA1 * 16 + q], uB1 = hp[sB1 * 16 + q];
        uint uA2 = hp[sA2 * 16 + q], uB2 = hp[sB2 * 16 + q];
        uint uA3 = hp[sA3 * 16 + q], uB3 = hp[sB3 * 16 + q];
        __half2 h0 = __hadd2(*(const __half2*)&uA0, *(const __half2*)&uB0);
        __half2 h1 = __hadd2(*(const __half2*)&uA1, *(const __half2*)&uB1);
        __half2 h2 = __hadd2(*(const __half2*)&uA2, *(const __half2*)&uB2);
        __half2 h3 = __hadd2(*(const __half2*)&uA3, *(const __half2*)&uB3);
        float2 f0 = __half22float2(h0), f1 = __half22float2(h1);
        float2 f2 = __half22float2(h2), f3 = __half22float2(h3);
        accx = (f0.x + f1.x) + (f2.x + f3.x);
        accy = (f0.y + f1.y) + (f2.y + f3.y);
        for (int j = lo + 32; j < hi; j += 8) {   // rare deg>32 tail
            int sA = csr_src[j + el], sB = csr_src[j + 4 + el];
            uint uA = hp[sA * 16 + q], uB = hp[sB * 16 + q];
            __half2 hs = __hadd2(*(const __half2*)&uA, *(const __half2*)&uB);
            float2 f = __half22float2(hs);
            accx += f.x; accy += f.y;
        }
    } else {                               // DIN == 16
        int el = lane >> 3;                // 8 edge slots; 1 edge/chunk/lane
        int b0 = lo + el;
        int s0 = csr_src[b0 +  0];
        int s1 = csr_src[b0 +  8];
        int s2 = csr_src[b0 + 16];
        int s3 = csr_src[b0 + 24];
        if (nch < 1) s0 = NN;
        if (nch < 2) s1 = NN;
        if (nch < 3) s2 = NN;
        if (nch < 4) s3 = NN;
        uint u0 = hp[s0 * 8 + q];
        uint u1 = hp[s1 * 8 + q];
        uint u2 = hp[s2 * 8 + q];
        uint u3 = hp[s3 * 8 + q];
        __half2 ha = __hadd2(*(const __half2*)&u0, *(const __half2*)&u1);
        __half2 hb = __hadd2(*(const __half2*)&u2, *(const __half2*)&u3);
        float2 fa = __half22float2(ha), fb = __half22float2(hb);
        accx = fa.x + fb.x;
        accy = fa.y + fb.y;
        for (int j = lo + 32; j < hi; j += 8) {   // rare deg>32 tail
            int s = csr_src[j + el];
            uint u = hp[s * 8 + q];
            float2 f = __half22float2(*(const __half2*)&u);
            accx += f.x; accy += f.y;
        }
    }
    // reduce across edge slots (lanes strided by PQ) -> all lanes hold full agg
#pragma unroll
    for (int off = PQ; off < 64; off <<= 1) {
        accx += __shfl_xor(accx, off, 64);
        accy += __shfl_xor(accy, off, 64);
    }
    // self loop + norm
    {
        uint us = hp[v * PQ + q];
        float2 fs = __half22float2(*(const __half2*)&us);
        accx += fs.x; accy += fs.y;
    }
    float dv = dinv[v];
    float a0 = accx * dv;                  // agg[2q]
    float a1 = accy * dv;                  // agg[2q+1]

    if constexpr (DIN == 32) {
        // replica-split epilogue: el handles f2 in [8*el, 8*el+8)
        int el2 = lane >> 4;
        int gl = lane & 15;
        int f2b = el2 * 8;
        if constexpr (DOUT == 32) {
            // adjacent outputs 2gl, 2gl+1 -> packed half2 store
            float o0 = 0.f, o1 = 0.f;
#pragma unroll
            for (int k = 0; k < 8; ++k) {
                int f2 = f2b + k;
                float src = (f2 & 1) ? a1 : a0;
                float hf = __shfl(src, f2 >> 1, 16);
                o0 = fmaf(hf, Wg[f2 * 32 + 2 * gl], o0);
                o1 = fmaf(hf, Wg[f2 * 32 + 2 * gl + 1], o1);
            }
            o0 += __shfl_xor(o0, 16, 64);
            o1 += __shfl_xor(o1, 16, 64);
            o0 += __shfl_xor(o0, 32, 64);
            o1 += __shfl_xor(o1, 32, 64);
            if (lane < 16) {
                float r0 = bg[2 * gl] + o0;
                float r1 = bg[2 * gl + 1] + o1;
                if (RELU) { r0 = fmaxf(r0, 0.f); r1 = fmaxf(r1, 0.f); }
                *reinterpret_cast<__half2*>(&hout_h[v * 32 + 2 * gl]) =
                    __floats2half2_rn(r0 * dv, r1 * dv);
            }
        } else {                           // DOUT == 16 (L7), never LAST
            float o0 = 0.f;
#pragma unroll
            for (int k = 0; k < 8; ++k) {
                int f2 = f2b + k;
                float src = (f2 & 1) ? a1 : a0;
                float hf = __shfl(src, f2 >> 1, 16);
                o0 = fmaf(hf, Wg[f2 * 16 + gl], o0);
            }
            o0 += __shfl_xor(o0, 16, 64);
            o0 += __shfl_xor(o0, 32, 64);
            if (lane < 16) {
                float r0 = bg[gl] + o0;
                if (RELU) r0 = fmaxf(r0, 0.f);
                hout_h[v * 16 + gl] = __float2half(r0 * dv);
            }
        }
    } else {                               // DIN == 16: original epilogue
        int g = lane & (DOUT - 1);
        float o = bg[g];
#pragma unroll
        for (int f2 = 0; f2 < DIN; ++f2) {
            float src = (f2 & 1) ? a1 : a0;
            float hf = __shfl(src, f2 >> 1, PQ);
            o = fmaf(hf, Wg[f2 * DOUT + g], o);
        }
        if (lane < DOUT) {
            if (LAST) {
                hout_f[v * DOUT + g] = o + xorig[v * 2 + g];
            } else {
                if (RELU) o = fmaxf(o, 0.f);
                hout_h[v * DOUT + g] = __float2half(o * dv);
            }
        }
    }
}

// ---------------- launch ----------------

extern "C" void kernel_launch(void* const* d_in, const int* in_sizes, int n_in,
                              void* d_out, int out_size, void* d_ws, size_t ws_size,
                              hipStream_t stream) {
    const float* x = (const float*)d_in[0];
    const int* ei = (const int*)d_in[1];  // int32 (harness converts integer inputs)
    const float* W[8];
    const float* B[8];
    for (int i = 0; i < 8; ++i) {
        W[i] = (const float*)d_in[2 + 2 * i];
        B[i] = (const float*)d_in[3 + 2 * i];
    }
    float* out = (float*)d_out;

    char* ws = (char*)d_ws;
    int*       deg     = (int*)      (ws + 0);          //  0.4 MB
    float*     dinv    = (float*)    (ws + 400128);     //  0.4 MB
    int*       rowptr  = (int*)      (ws + 800256);     //  0.4 MB (n+1)
    int*       exc     = (int*)      (ws + 1200384);    //  0.4 MB
    int*       bsum    = (int*)      (ws + 1600512);    //  tiny
    int*       bcur    = (int*)      (ws + 1601024);    //  tiny
    long long* pairs   = (long long*)(ws + 1601536);    // 14.45 MB
    int*       csr_src = (int*)      (ws + 16052224);   //  9.6 MB (padded + slack)
    __half*    hdA     = (__half*)   (ws + 25652224);   //  6.4 MB + dummy row
    __half*    hdB     = (__half*)   (ws + 32052352);   //  6.4 MB + dummy row (total ~38.5 MB)

    dim3 blk(256);

    k_init<<<1, 128, 0, stream>>>(bcur);
    k_bucket<<<NBE, blk, 0, stream>>>(ei, bcur, pairs, NE);
    k_count2<<<NBUCK, blk, 0, stream>>>(pairs, bcur, deg);
    k_scan1<<<NBLK, SCAN_BLK, 0, stream>>>(deg, exc, bsum, NN);
    k_scan2<<<1, 128, 0, stream>>>(bsum, NBLK);
    k_scan3<<<NBLK, SCAN_BLK, 0, stream>>>(exc, bsum, deg, x, rowptr, dinv, (__half2*)hdA, NN);
    k_fill3<<<NBUCK, blk, 0, stream>>>(pairs, bcur, rowptr, csr_src);

    int gS = NN / 4 + 1;        // wave-per-node: 4 nodes/block (+1 dummy)
    int gL = (NN + 3) / 4;      // LAST: no dummy needed

    // L1: hdA(2) -> hdB(16)
    k_layer1<<<gS, blk, 0, stream>>>(rowptr, csr_src, (const __half2*)hdA, W[0], B[0], dinv, hdB, NN);
    // L2: hdB(16) -> hdA(32)
    k_layerU<16, 32, true, false><<<gS, blk, 0, stream>>>(rowptr, csr_src, hdB, W[1], B[1], dinv, x, hdA, out, NN);
    // L3: hdA(32) -> hdB(32)
    k_layerU<32, 32, true, false><<<gS, blk, 0, stream>>>(rowptr, csr_src, hdA, W[2], B[2], dinv, x, hdB, out, NN);
    // L4: hdB -> hdA
    k_layerU<32, 32, true, false><<<gS, blk, 0, stream>>>(rowptr, csr_src, hdB, W[3], B[3], dinv, x, hdA, out, NN);
    // L5: hdA -> hdB
    k_layerU<32, 32, true, false><<<gS, blk, 0, stream>>>(rowptr, csr_src, hdA, W[4], B[4], dinv, x, hdB, out, NN);
    // L6: hdB -> hdA
    k_layerU<32, 32, true, false><<<gS, blk, 0, stream>>>(rowptr, csr_src, hdB, W[5], B[5], dinv, x, hdA, out, NN);
    // L7: hdA(32) -> hdB(16)
    k_layerU<32, 16, true, false><<<gS, blk, 0, stream>>>(rowptr, csr_src, hdA, W[6], B[6], dinv, x, hdB, out, NN);
    // L8: hdB(16) -> out(2), +x_orig, no relu
    k_layerU<16, 2, false, true><<<gL, blk, 0, stream>>>(rowptr, csr_src, hdB, W[7], B[7], dinv, x, hdA, out, NN);
}

// Round 21
// 343.480 us; speedup vs baseline: 1.1231x; 1.1231x over previous
//
#include <hip/hip_runtime.h>
#include <hip/hip_fp16.h>

#define NN 100000
#define NE 1600000
#define SCAN_BLK 1024
#define NBLK ((NN + SCAN_BLK - 1) / SCAN_BLK)   // 98

#define EB 6144                                  // edges per bucket-block chunk
#define NBE ((NE + EB - 1) / EB)                 // 261
#define BSH 10                                   // 1024-node buckets
#define NBUCK ((NN + 1023) >> BSH)               // 98
#define BCAP 18432                               // pairs cap/bucket (exp 16327, sd ~127)

// ---------------- structure precompute ----------------

__global__ void k_init(int* __restrict__ bcur) {
    int i = blockIdx.x * blockDim.x + threadIdx.x;
    if (i < NBUCK) bcur[i] = i * BCAP;
}

// chunk edges -> per-bucket contiguous runs of (dst,src) pairs
__global__ __launch_bounds__(256) void k_bucket(
    const int* __restrict__ ei, int* __restrict__ bcur,
    long long* __restrict__ pairs, int nE) {
    __shared__ int cnt[NBUCK];
    __shared__ int sc[NBUCK];
    __shared__ int rc[NBUCK];
    __shared__ int gbase[NBUCK];
    __shared__ int tmp[256];
    __shared__ long long st[EB];

    int base = blockIdx.x * EB;
    int lim = nE - base; if (lim > EB) lim = EB;
    int tid = threadIdx.x;

    for (int i = tid; i < NBUCK; i += 256) cnt[i] = 0;
    __syncthreads();
    for (int i = tid; i < lim; i += 256) {
        int d = ei[nE + base + i];
        atomicAdd(&cnt[d >> BSH], 1);
    }
    __syncthreads();
    {
        int v = (tid < NBUCK) ? cnt[tid] : 0;
        tmp[tid] = v;
        __syncthreads();
        for (int off = 1; off < 256; off <<= 1) {
            int add = (tid >= off) ? tmp[tid - off] : 0;
            __syncthreads();
            tmp[tid] += add;
            __syncthreads();
        }
        if (tid < NBUCK) {
            int e = tmp[tid] - v;
            sc[tid] = e;
            rc[tid] = e;
            gbase[tid] = (v > 0) ? atomicAdd(&bcur[tid], v) : 0;
        }
    }
    __syncthreads();
    for (int i = tid; i < lim; i += 256) {
        int s = ei[base + i];
        int d = ei[nE + base + i];
        int p = atomicAdd(&rc[d >> BSH], 1);
        st[p] = ((long long)d << 32) | (unsigned int)s;
    }
    __syncthreads();
    for (int i = tid; i < lim; i += 256) {
        long long pr = st[i];
        int b = (int)(pr >> 32) >> BSH;
        pairs[gbase[b] + (i - sc[b])] = pr;
    }
}

// per-bucket LDS histogram -> coalesced non-atomic deg write
__global__ __launch_bounds__(256) void k_count2(
    const long long* __restrict__ pairs, const int* __restrict__ bcur,
    int* __restrict__ deg) {
    __shared__ int cnt[1 << BSH];
    int b = blockIdx.x;
    int gb = b * BCAP;
    int m = bcur[b] - gb;
    for (int i = threadIdx.x; i < (1 << BSH); i += 256) cnt[i] = 0;
    __syncthreads();
    for (int i = threadIdx.x; i < m; i += 256) {
        int d = (int)(pairs[gb + i] >> 32);
        atomicAdd(&cnt[d & ((1 << BSH) - 1)], 1);
    }
    __syncthreads();
    int base = b << BSH;
    for (int i = threadIdx.x; i < (1 << BSH); i += 256) {
        int v = base + i;
        if (v < NN) deg[v] = cnt[i];
    }
}

// scan over PADDED degrees: pdeg = (deg+7)&~7
__global__ __launch_bounds__(SCAN_BLK) void k_scan1(
    const int* __restrict__ deg, int* __restrict__ exc, int* __restrict__ bsum, int n) {
    __shared__ int sh[SCAN_BLK];
    int tid = threadIdx.x;
    int i = blockIdx.x * SCAN_BLK + tid;
    int v = (i < n) ? ((deg[i] + 7) & ~7) : 0;
    sh[tid] = v;
    __syncthreads();
    for (int off = 1; off < SCAN_BLK; off <<= 1) {
        int add = (tid >= off) ? sh[tid - off] : 0;
        __syncthreads();
        sh[tid] += add;
        __syncthreads();
    }
    if (i < n) exc[i] = sh[tid] - v;
    if (tid == SCAN_BLK - 1) bsum[blockIdx.x] = sh[tid];
}

__global__ __launch_bounds__(128) void k_scan2(int* __restrict__ bsum, int nb) {
    __shared__ int sh[128];
    int tid = threadIdx.x;
    int v = (tid < nb) ? bsum[tid] : 0;
    sh[tid] = v;
    __syncthreads();
    for (int off = 1; off < 128; off <<= 1) {
        int add = (tid >= off) ? sh[tid - off] : 0;
        __syncthreads();
        sh[tid] += add;
        __syncthreads();
    }
    if (tid < nb) bsum[tid] = sh[tid] - v;  // exclusive
}

// rowptr (padded) + dinv + hd0 = x*dinv (fp16) + dummy row + total
__global__ __launch_bounds__(SCAN_BLK) void k_scan3(
    const int* __restrict__ exc, const int* __restrict__ bsum,
    const int* __restrict__ deg, const float* __restrict__ x,
    int* __restrict__ rowptr, float* __restrict__ dinv,
    __half2* __restrict__ hd0, int n) {
    int i = blockIdx.x * SCAN_BLK + threadIdx.x;
    if (i >= n) return;
    int r = exc[i] + bsum[blockIdx.x];
    rowptr[i] = r;
    float dv = rsqrtf((float)(deg[i] + 1));  // +1 = self loop
    dinv[i] = dv;
    hd0[i] = __floats2half2_rn(x[2 * i] * dv, x[2 * i + 1] * dv);
    if (i == n - 1) rowptr[n] = r + ((deg[i] + 7) & ~7);
    if (i == 0) hd0[n] = __floats2half2_rn(0.f, 0.f);  // dummy row (pad target)
}

// per-bucket scatter with LDS cursors; then write pad entries (src = NN dummy)
__global__ __launch_bounds__(256) void k_fill3(
    const long long* __restrict__ pairs, const int* __restrict__ bcur,
    const int* __restrict__ rowptr, int* __restrict__ csr_src) {
    __shared__ int lcur[1 << BSH];
    int b = blockIdx.x;
    int gb = b * BCAP;
    int m = bcur[b] - gb;
    int base = b << BSH;
    for (int i = threadIdx.x; i < (1 << BSH); i += 256) {
        int v = base + i;
        lcur[i] = (v < NN) ? rowptr[v] : 0;
    }
    __syncthreads();
    for (int i = threadIdx.x; i < m; i += 256) {
        long long pr = pairs[gb + i];
        int d = (int)(pr >> 32);
        int s = (int)(pr & 0xffffffffLL);
        int pos = atomicAdd(&lcur[d & ((1 << BSH) - 1)], 1);
        csr_src[pos] = s;
    }
    __syncthreads();
    for (int i = threadIdx.x; i < (1 << BSH); i += 256) {
        int v = base + i;
        if (v < NN) {
            int e = lcur[i];          // rowptr[v] + deg[v]
            int pe = rowptr[v + 1];   // padded end
            for (; e < pe; ++e) csr_src[e] = NN;
        }
    }
}

// ---------------- layer kernels ----------------
// agg[v] = dinv[v] * (sum_j hd_in[src_j] + hd_in[v]) ; o = agg@W + b
// hd_out = relu(o)*dinv (fp16)   |  LAST: out = o + xorig (fp32)
// Rows padded to x8 with dummy src NN (zero row).
// NOTE (r20 lesson): keep (size_t) index math in gathers — hipcc emits
// v_mad_u64_u32 for it; int indexing forces sext + carry chains (slower).

// L1: DIN=2, half2 rows; 16-lane edge-split + butterfly.
__global__ __launch_bounds__(256) void k_layer1(
    const int* __restrict__ rowptr, const int* __restrict__ csr_src,
    const __half2* __restrict__ hd0, const float* __restrict__ Wg,
    const float* __restrict__ bg, const float* __restrict__ dinv,
    __half* __restrict__ hd1, int n) {
    __shared__ float sW[32];
    if (threadIdx.x < 32) sW[threadIdx.x] = Wg[threadIdx.x];
    __syncthreads();
    int v = blockIdx.x * 16 + threadIdx.x / 16;
    int l = threadIdx.x & 15;
    if (v > n) return;
    if (v == n) { hd1[v * 16 + l] = __float2half(0.f); return; }  // dummy row
    int lo = rowptr[v], hi = rowptr[v + 1];
    float a0 = 0.f, a1 = 0.f;
    for (int j = lo + l; j < hi; j += 16) {
        float2 h = __half22float2(hd0[csr_src[j]]);
        a0 += h.x; a1 += h.y;
    }
#pragma unroll
    for (int off = 8; off >= 1; off >>= 1) {
        a0 += __shfl_xor(a0, off, 16);
        a1 += __shfl_xor(a1, off, 16);
    }
    float dv = dinv[v];
    float2 hs = __half22float2(hd0[v]);
    a0 = (a0 + hs.x) * dv;
    a1 = (a1 + hs.y) * dv;
    float o = bg[l] + a0 * sW[l] + a1 * sW[16 + l];   // W is (2,16) row-major
    hd1[v * 16 + l] = __float2half(fmaxf(o, 0.f) * dv);
}

// Unrolled-burst layer (round-16 structure) + replica-split epilogue for
// DIN=32: each of the 4 edge-slot replicas handles 8 f2 terms (2 output
// accumulators g, g+16), combined by 2 shfl_xor.
template <int DIN, int DOUT, bool RELU, bool LAST>
__global__ __launch_bounds__(256) void k_layerU(
    const int* __restrict__ rowptr, const int* __restrict__ csr_src,
    const __half* __restrict__ hd_in, const float* __restrict__ Wg,
    const float* __restrict__ bg, const float* __restrict__ dinv,
    const float* __restrict__ xorig, __half* __restrict__ hout_h,
    float* __restrict__ hout_f, int n) {
    constexpr int PQ = DIN / 2;           // uints per row
    int lane = threadIdx.x & 63;

    int v = blockIdx.x * 4 + (threadIdx.x >> 6);
    if (v > n) return;
    if (v == n) {                          // dummy row for next layer's pads
        if (!LAST && lane < DOUT) hout_h[(size_t)v * DOUT + lane] = __float2half(0.f);
        return;
    }
    int q = lane & (PQ - 1);
    int lo = rowptr[v], hi = rowptr[v + 1];   // (hi-lo)%8==0
    int nch = (hi - lo) >> 3;
    const uint* hp = (const uint*)hd_in;
    float accx = 0.f, accy = 0.f;

    if constexpr (DIN == 32) {
        int el = lane >> 4;                // 4 edge slots; 2 edges/chunk/lane
        int b0 = lo + el;
        int sA0 = csr_src[b0 +  0], sB0 = csr_src[b0 +  4];
        int sA1 = csr_src[b0 +  8], sB1 = csr_src[b0 + 12];
        int sA2 = csr_src[b0 + 16], sB2 = csr_src[b0 + 20];
        int sA3 = csr_src[b0 + 24], sB3 = csr_src[b0 + 28];
        if (nch < 1) { sA0 = NN; sB0 = NN; }
        if (nch < 2) { sA1 = NN; sB1 = NN; }
        if (nch < 3) { sA2 = NN; sB2 = NN; }
        if (nch < 4) { sA3 = NN; sB3 = NN; }
        uint uA0 = hp[(size_t)sA0 * 16 + q], uB0 = hp[(size_t)sB0 * 16 + q];
        uint uA1 = hp[(size_t)sA1 * 16 + q], uB1 = hp[(size_t)sB1 * 16 + q];
        uint uA2 = hp[(size_t)sA2 * 16 + q], uB2 = hp[(size_t)sB2 * 16 + q];
        uint uA3 = hp[(size_t)sA3 * 16 + q], uB3 = hp[(size_t)sB3 * 16 + q];
        __half2 h0 = __hadd2(*(const __half2*)&uA0, *(const __half2*)&uB0);
        __half2 h1 = __hadd2(*(const __half2*)&uA1, *(const __half2*)&uB1);
        __half2 h2 = __hadd2(*(const __half2*)&uA2, *(const __half2*)&uB2);
        __half2 h3 = __hadd2(*(const __half2*)&uA3, *(const __half2*)&uB3);
        float2 f0 = __half22float2(h0), f1 = __half22float2(h1);
        float2 f2 = __half22float2(h2), f3 = __half22float2(h3);
        accx = (f0.x + f1.x) + (f2.x + f3.x);
        accy = (f0.y + f1.y) + (f2.y + f3.y);
        for (int j = lo + 32; j < hi; j += 8) {   // rare deg>32 tail
            int sA = csr_src[j + el], sB = csr_src[j + 4 + el];
            uint uA = hp[(size_t)sA * 16 + q], uB = hp[(size_t)sB * 16 + q];
            __half2 hs = __hadd2(*(const __half2*)&uA, *(const __half2*)&uB);
            float2 f = __half22float2(hs);
            accx += f.x; accy += f.y;
        }
    } else {                               // DIN == 16
        int el = lane >> 3;                // 8 edge slots; 1 edge/chunk/lane
        int b0 = lo + el;
        int s0 = csr_src[b0 +  0];
        int s1 = csr_src[b0 +  8];
        int s2 = csr_src[b0 + 16];
        int s3 = csr_src[b0 + 24];
        if (nch < 1) s0 = NN;
        if (nch < 2) s1 = NN;
        if (nch < 3) s2 = NN;
        if (nch < 4) s3 = NN;
        uint u0 = hp[(size_t)s0 * 8 + q];
        uint u1 = hp[(size_t)s1 * 8 + q];
        uint u2 = hp[(size_t)s2 * 8 + q];
        uint u3 = hp[(size_t)s3 * 8 + q];
        __half2 ha = __hadd2(*(const __half2*)&u0, *(const __half2*)&u1);
        __half2 hb = __hadd2(*(const __half2*)&u2, *(const __half2*)&u3);
        float2 fa = __half22float2(ha), fb = __half22float2(hb);
        accx = fa.x + fb.x;
        accy = fa.y + fb.y;
        for (int j = lo + 32; j < hi; j += 8) {   // rare deg>32 tail
            int s = csr_src[j + el];
            uint u = hp[(size_t)s * 8 + q];
            float2 f = __half22float2(*(const __half2*)&u);
            accx += f.x; accy += f.y;
        }
    }
    // reduce across edge slots (lanes strided by PQ) -> all lanes hold full agg
#pragma unroll
    for (int off = PQ; off < 64; off <<= 1) {
        accx += __shfl_xor(accx, off, 64);
        accy += __shfl_xor(accy, off, 64);
    }
    // self loop + norm
    {
        uint us = hp[(size_t)v * PQ + q];
        float2 fs = __half22float2(*(const __half2*)&us);
        accx += fs.x; accy += fs.y;
    }
    float dv = dinv[v];
    float a0 = accx * dv;                  // agg[2q]
    float a1 = accy * dv;                  // agg[2q+1]

    if constexpr (DIN == 32) {
        // replica-split epilogue: el handles f2 in [8*el, 8*el+8)
        int el2 = lane >> 4;
        int gl = lane & 15;
        int f2b = el2 * 8;
        if constexpr (DOUT == 32) {
            float o0 = 0.f, o1 = 0.f;
#pragma unroll
            for (int k = 0; k < 8; ++k) {
                int f2 = f2b + k;
                float src = (f2 & 1) ? a1 : a0;
                float hf = __shfl(src, f2 >> 1, 16);
                o0 = fmaf(hf, Wg[f2 * 32 + gl], o0);
                o1 = fmaf(hf, Wg[f2 * 32 + gl + 16], o1);
            }
            o0 += __shfl_xor(o0, 16, 64);
            o1 += __shfl_xor(o1, 16, 64);
            o0 += __shfl_xor(o0, 32, 64);
            o1 += __shfl_xor(o1, 32, 64);
            if (lane < 16) {
                float r0 = bg[gl] + o0;
                float r1 = bg[gl + 16] + o1;
                if (RELU) { r0 = fmaxf(r0, 0.f); r1 = fmaxf(r1, 0.f); }
                hout_h[(size_t)v * 32 + gl]      = __float2half(r0 * dv);
                hout_h[(size_t)v * 32 + gl + 16] = __float2half(r1 * dv);
            }
        } else {                           // DOUT == 16 (L7), never LAST
            float o0 = 0.f;
#pragma unroll
            for (int k = 0; k < 8; ++k) {
                int f2 = f2b + k;
                float src = (f2 & 1) ? a1 : a0;
                float hf = __shfl(src, f2 >> 1, 16);
                o0 = fmaf(hf, Wg[f2 * 16 + gl], o0);
            }
            o0 += __shfl_xor(o0, 16, 64);
            o0 += __shfl_xor(o0, 32, 64);
            if (lane < 16) {
                float r0 = bg[gl] + o0;
                if (RELU) r0 = fmaxf(r0, 0.f);
                hout_h[(size_t)v * 16 + gl] = __float2half(r0 * dv);
            }
        }
    } else {                               // DIN == 16: original epilogue
        int g = lane & (DOUT - 1);
        float o = bg[g];
#pragma unroll
        for (int f2 = 0; f2 < DIN; ++f2) {
            float src = (f2 & 1) ? a1 : a0;
            float hf = __shfl(src, f2 >> 1, PQ);
            o = fmaf(hf, Wg[f2 * DOUT + g], o);
        }
        if (lane < DOUT) {
            if (LAST) {
                hout_f[(size_t)v * DOUT + g] = o + xorig[(size_t)v * 2 + g];
            } else {
                if (RELU) o = fmaxf(o, 0.f);
                hout_h[(size_t)v * DOUT + g] = __float2half(o * dv);
            }
        }
    }
}

// ---------------- launch ----------------

extern "C" void kernel_launch(void* const* d_in, const int* in_sizes, int n_in,
                              void* d_out, int out_size, void* d_ws, size_t ws_size,
                              hipStream_t stream) {
    const float* x = (const float*)d_in[0];
    const int* ei = (const int*)d_in[1];  // int32 (harness converts integer inputs)
    const float* W[8];
    const float* B[8];
    for (int i = 0; i < 8; ++i) {
        W[i] = (const float*)d_in[2 + 2 * i];
        B[i] = (const float*)d_in[3 + 2 * i];
    }
    float* out = (float*)d_out;

    char* ws = (char*)d_ws;
    int*       deg     = (int*)      (ws + 0);          //  0.4 MB
    float*     dinv    = (float*)    (ws + 400128);     //  0.4 MB
    int*       rowptr  = (int*)      (ws + 800256);     //  0.4 MB (n+1)
    int*       exc     = (int*)      (ws + 1200384);    //  0.4 MB
    int*       bsum    = (int*)      (ws + 1600512);    //  tiny
    int*       bcur    = (int*)      (ws + 1601024);    //  tiny
    long long* pairs   = (long long*)(ws + 1601536);    // 14.45 MB
    int*       csr_src = (int*)      (ws + 16052224);   //  9.6 MB (padded + slack)
    __half*    hdA     = (__half*)   (ws + 25652224);   //  6.4 MB + dummy row
    __half*    hdB     = (__half*)   (ws + 32052352);   //  6.4 MB + dummy row (total ~38.5 MB)

    dim3 blk(256);

    k_init<<<1, 128, 0, stream>>>(bcur);
    k_bucket<<<NBE, blk, 0, stream>>>(ei, bcur, pairs, NE);
    k_count2<<<NBUCK, blk, 0, stream>>>(pairs, bcur, deg);
    k_scan1<<<NBLK, SCAN_BLK, 0, stream>>>(deg, exc, bsum, NN);
    k_scan2<<<1, 128, 0, stream>>>(bsum, NBLK);
    k_scan3<<<NBLK, SCAN_BLK, 0, stream>>>(exc, bsum, deg, x, rowptr, dinv, (__half2*)hdA, NN);
    k_fill3<<<NBUCK, blk, 0, stream>>>(pairs, bcur, rowptr, csr_src);

    int g1 = (NN + 16) / 16;    // k_layer1: 16 nodes/block (+1 dummy)
    int gS = NN / 4 + 1;        // wave-per-node: 4 nodes/block (+1 dummy)
    int gL = (NN + 3) / 4;      // LAST: no dummy needed

    // L1: hdA(2) -> hdB(16)
    k_layer1<<<g1, blk, 0, stream>>>(rowptr, csr_src, (const __half2*)hdA, W[0], B[0], dinv, hdB, NN);
    // L2: hdB(16) -> hdA(32)
    k_layerU<16, 32, true, false><<<gS, blk, 0, stream>>>(rowptr, csr_src, hdB, W[1], B[1], dinv, x, hdA, out, NN);
    // L3: hdA(32) -> hdB(32)
    k_layerU<32, 32, true, false><<<gS, blk, 0, stream>>>(rowptr, csr_src, hdA, W[2], B[2], dinv, x, hdB, out, NN);
    // L4: hdB -> hdA
    k_layerU<32, 32, true, false><<<gS, blk, 0, stream>>>(rowptr, csr_src, hdB, W[3], B[3], dinv, x, hdA, out, NN);
    // L5: hdA -> hdB
    k_layerU<32, 32, true, false><<<gS, blk, 0, stream>>>(rowptr, csr_src, hdA, W[4], B[4], dinv, x, hdB, out, NN);
    // L6: hdB -> hdA
    k_layerU<32, 32, true, false><<<gS, blk, 0, stream>>>(rowptr, csr_src, hdB, W[5], B[5], dinv, x, hdA, out, NN);
    // L7: hdA(32) -> hdB(16)
    k_layerU<32, 16, true, false><<<gS, blk, 0, stream>>>(rowptr, csr_src, hdA, W[6], B[6], dinv, x, hdB, out, NN);
    // L8: hdB(16) -> out(2), +x_orig, no relu
    k_layerU<16, 2, false, true><<<gL, blk, 0, stream>>>(rowptr, csr_src, hdB, W[7], B[7], dinv, x, hdA, out, NN);
}